// Round 9
// baseline (220.565 us; speedup 1.0000x reference)
//
#include <hip/hip_runtime.h>
#include <hip/hip_bf16.h>

#define BB 64
#define SS 2048
#define DD 512
#define MTOT (BB * SS)          // 131072 rows

typedef __attribute__((ext_vector_type(8))) short short8;   // 8 bf16
typedef __attribute__((ext_vector_type(4))) short s16x4;    // 4 bf16
typedef __attribute__((ext_vector_type(4))) float f32x4;

// fp32->bf16 RNE; compiler fuses pairs into v_cvt_pk_bf16_f32
__device__ __forceinline__ short f2bf(float f){
  __hip_bfloat16 h = __float2bfloat16(f);
  return *reinterpret_cast<short*>(&h);
}
__device__ __forceinline__ short8 pack8(float4 a, float4 b){
  short8 u;
  u[0]=f2bf(a.x); u[1]=f2bf(a.y); u[2]=f2bf(a.z); u[3]=f2bf(a.w);
  u[4]=f2bf(b.x); u[5]=f2bf(b.y); u[6]=f2bf(b.z); u[7]=f2bf(b.w);
  return u;
}
__device__ __forceinline__ s16x4 pack4(float4 a){
  s16x4 u;
  u[0]=f2bf(a.x); u[1]=f2bf(a.y); u[2]=f2bf(a.z); u[3]=f2bf(a.w);
  return u;
}

// ---- kernel 1: W1 fp32 -> bf16, plain row-major [e][d] ----
__global__ void cvt_w1_kernel(const float* __restrict__ W1, unsigned short* __restrict__ W1b){
  int i = blockIdx.x * blockDim.x + threadIdx.x;   // 32768 threads x 8 elems
  const float* src = W1 + (size_t)i * 8;
  float4 f0 = *(const float4*)src;
  float4 f1 = *(const float4*)(src + 4);
  *(short8*)(W1b + (size_t)i * 8) = pack8(f0, f1);
}

// ---- kernel 2: scores = sum_e tanh(x@W1^T + b1)[.,e] * w2[e] ----
// BM=64, BN=512, BK=32, 16 steps, 512 thr / 8 waves, wave-tile 64x64 (acc[4][4]).
// A: LDS (8-way intra-block reuse): all-512-thread staging, depth-2 reg
//    prefetch, 2 x 4KB slices, swizzle kgrp^((row>>1)&3) (R8: 0 conflicts).
// B: NO LDS (zero intra-block reuse) — L2->reg double-buffer, loaded 1 step
//    ahead; stays in per-wave flight across barriers (compiler counted vmcnt).
// Barrier: lgkmcnt(0) + raw s_barrier + sched_barrier(0) only.
// LDS 10KB, regs target 64V+64A -> 2 blocks/CU.
__launch_bounds__(512, 4)
__global__ void scores_kernel(const float* __restrict__ x,
                              const unsigned short* __restrict__ W1b,
                              const float* __restrict__ b1,
                              const float* __restrict__ w2,
                              float* __restrict__ scorep){
  __shared__ __align__(16) unsigned short Abuf[2][2048];   // 2 x 4KB
  __shared__ float psum[8 * 64];

  const int t    = threadIdx.x;
  const int lane = t & 63;
  const int wid  = t >> 6;
  const int m0   = blockIdx.x * 64;
  const int arow = lane & 15;
  const int kgrp = lane >> 4;

  f32x4 acc[4][4];
  #pragma unroll
  for (int mt = 0; mt < 4; ++mt)
    #pragma unroll
    for (int et = 0; et < 4; ++et)
      acc[mt][et] = (f32x4){0.f, 0.f, 0.f, 0.f};

  // A staging: all 512 threads, 1 float4/step. r=t>>3 (0..63), q=t&7
  const int ar = t >> 3;
  const int aq = t & 7;
  const float* asrc = x + (size_t)(m0 + ar) * DD + aq * 4;
  const int awoff = ((((ar << 2) + ((aq >> 1) ^ ((ar >> 1) & 3))) << 4) + ((aq & 1) << 3));

  // B bases: 4 per-lane pointers (row e0+et*16, k-chunk kgrp*8); step = imm offset
  const int e0 = (wid << 6) + arow;
  const unsigned short* bp0 = W1b + (size_t)(e0 +  0) * DD + kgrp * 8;
  const unsigned short* bp1 = W1b + (size_t)(e0 + 16) * DD + kgrp * 8;
  const unsigned short* bp2 = W1b + (size_t)(e0 + 32) * DD + kgrp * 8;
  const unsigned short* bp3 = W1b + (size_t)(e0 + 48) * DD + kgrp * 8;

  short8 bb[2][4];
  float4 areg[2];

  // ---- prologue: B(0); A(0); A(1); cvt A(0)->slice0 ----
  bb[0][0] = *(const short8*)bp0;
  bb[0][1] = *(const short8*)bp1;
  bb[0][2] = *(const short8*)bp2;
  bb[0][3] = *(const short8*)bp3;
  float4 p0 = *(const float4*)asrc;
  areg[1] = *(const float4*)(asrc + 32);
  *(s16x4*)((char*)&Abuf[0][0] + awoff) = pack4(p0);
  asm volatile("s_waitcnt lgkmcnt(0)" ::: "memory");
  __builtin_amdgcn_s_barrier();
  __builtin_amdgcn_sched_barrier(0);

  // ---- main loop: 16 k-steps of 32, fully unrolled ----
  #pragma unroll
  for (int s = 0; s < 16; ++s){
    // 1. issue B(s+1) -> other reg buffer (L2, ~1 step of cover)
    if (s < 15){
      bb[(s + 1) & 1][0] = *(const short8*)(bp0 + (s + 1) * 32);
      bb[(s + 1) & 1][1] = *(const short8*)(bp1 + (s + 1) * 32);
      bb[(s + 1) & 1][2] = *(const short8*)(bp2 + (s + 1) * 32);
      bb[(s + 1) & 1][3] = *(const short8*)(bp3 + (s + 1) * 32);
    }
    // 2. issue A(s+2) (HBM, 2 steps of cover; in flight across barriers)
    if (s < 14)
      areg[s & 1] = *(const float4*)(asrc + (s + 2) * 32);

    // 3+4. per-mt: ds_read af then 4 MFMA (af live = 1 -> low VGPR)
    __builtin_amdgcn_s_setprio(1);
    #pragma unroll
    for (int mt = 0; mt < 4; ++mt){
      int row = mt * 16 + arow;
      short8 af = *(const short8*)((char*)&Abuf[s & 1][0]
                + (((row << 2) + (kgrp ^ ((row >> 1) & 3))) << 4));
      #pragma unroll
      for (int et = 0; et < 4; ++et)
        acc[mt][et] = __builtin_amdgcn_mfma_f32_16x16x32_bf16(af, bb[s & 1][et], acc[mt][et], 0, 0, 0);
    }
    __builtin_amdgcn_s_setprio(0);

    // 5. cvt+write A(s+1) (loaded at s-1; retirement wait ~free)
    if (s < 15)
      *(s16x4*)((char*)&Abuf[(s + 1) & 1][0] + awoff) = pack4(areg[(s + 1) & 1]);

    // 6. LDS-only barrier: B and A prefetches stay in flight
    if (s < 15){
      asm volatile("s_waitcnt lgkmcnt(0)" ::: "memory");
      __builtin_amdgcn_s_barrier();
      __builtin_amdgcn_sched_barrier(0);
    }
  }

  // ---- epilogue: tanh + dot(w2), reduce over e ----
  float ps[4][4];
  #pragma unroll
  for (int mt = 0; mt < 4; ++mt)
    #pragma unroll
    for (int i = 0; i < 4; ++i) ps[mt][i] = 0.f;

  #pragma unroll
  for (int et = 0; et < 4; ++et){
    int e = (wid << 6) + (et << 4) + arow;     // C/D col = lane&15
    float b1v = b1[e];
    float w2v = w2[e];
    #pragma unroll
    for (int mt = 0; mt < 4; ++mt){
      #pragma unroll
      for (int i = 0; i < 4; ++i){
        float g = acc[mt][et][i] + b1v;
        g = fminf(15.f, fmaxf(-15.f, g));
        float ex = __expf(2.f * g);
        ps[mt][i] += (1.f - 2.f / (ex + 1.f)) * w2v;   // tanh(g)*w2
      }
    }
  }
  #pragma unroll
  for (int mt = 0; mt < 4; ++mt)
    #pragma unroll
    for (int i = 0; i < 4; ++i){
      float v = ps[mt][i];
      v += __shfl_xor(v, 1);
      v += __shfl_xor(v, 2);
      v += __shfl_xor(v, 4);
      v += __shfl_xor(v, 8);
      ps[mt][i] = v;
    }
  if ((lane & 15) == 0){
    #pragma unroll
    for (int mt = 0; mt < 4; ++mt)
      #pragma unroll
      for (int i = 0; i < 4; ++i)
        psum[wid * 64 + mt * 16 + (lane >> 4) * 4 + i] = ps[mt][i];
  }
  __syncthreads();
  if (t < 64){
    float ssum = 0.f;
    #pragma unroll
    for (int w = 0; w < 8; ++w) ssum += psum[w * 64 + t];
    scorep[m0 + t] = ssum;    // pre-softmax; b2 softmax-invariant
  }
}

// ---- kernel 3: row softmax -> w ----
__global__ void softmax_kernel(const float* __restrict__ scorep, float* __restrict__ wout){
  const int b = blockIdx.x;
  const int t = threadIdx.x;                 // 256
  float v[8];
  #pragma unroll
  for (int i = 0; i < 8; ++i) v[i] = scorep[(size_t)b * SS + t + i * 256];
  float m = v[0];
  #pragma unroll
  for (int i = 1; i < 8; ++i) m = fmaxf(m, v[i]);
  #pragma unroll
  for (int msk = 32; msk >= 1; msk >>= 1) m = fmaxf(m, __shfl_xor(m, msk));
  __shared__ float redm[4], reds[4];
  if ((t & 63) == 0) redm[t >> 6] = m;
  __syncthreads();
  m = fmaxf(fmaxf(redm[0], redm[1]), fmaxf(redm[2], redm[3]));
  float s = 0.f;
  #pragma unroll
  for (int i = 0; i < 8; ++i){ v[i] = __expf(v[i] - m); s += v[i]; }
  #pragma unroll
  for (int msk = 32; msk >= 1; msk >>= 1) s += __shfl_xor(s, msk);
  if ((t & 63) == 0) reds[t >> 6] = s;
  __syncthreads();
  s = reds[0] + reds[1] + reds[2] + reds[3];
  float inv = 1.f / s;
  #pragma unroll
  for (int i = 0; i < 8; ++i) wout[(size_t)b * SS + t + i * 256] = v[i] * inv;
}

// ---- kernel 4: ctx partials (fp32 x, no atomics; HBM-roofline) ----
__global__ void ctx_partial_kernel(const float* __restrict__ x, const float* __restrict__ wout,
                                   float* __restrict__ ctxp){
  __shared__ float red[4][512];
  const int t   = threadIdx.x;
  const int sub = t >> 7;                    // 0..3 (wave-uniform)
  const int dt  = t & 127;                   // d = dt*4
  const int b   = blockIdx.x >> 3;
  const int sc  = blockIdx.x & 7;
  const float* xb = x + (size_t)b * SS * DD;
  const int s0 = sc * 256 + sub * 64;
  float4 acc = {0.f, 0.f, 0.f, 0.f};
  for (int s = s0; s < s0 + 64; ++s){
    float wv = wout[(size_t)b * SS + s];     // wave-uniform -> scalar load
    float4 xv = *(const float4*)(xb + (size_t)s * DD + dt * 4);
    acc.x += wv * xv.x; acc.y += wv * xv.y; acc.z += wv * xv.z; acc.w += wv * xv.w;
  }
  *(float4*)&red[sub][dt * 4] = acc;
  __syncthreads();
  if (t < 128){
    float4 r0 = *(const float4*)&red[0][t * 4];
    float4 r1 = *(const float4*)&red[1][t * 4];
    float4 r2 = *(const float4*)&red[2][t * 4];
    float4 r3 = *(const float4*)&red[3][t * 4];
    float4 o = { r0.x+r1.x+r2.x+r3.x, r0.y+r1.y+r2.y+r3.y,
                 r0.z+r1.z+r2.z+r3.z, r0.w+r1.w+r2.w+r3.w };
    *(float4*)&ctxp[((size_t)(b * 8 + sc)) * DD + t * 4] = o;
  }
}

// ---- kernel 5: reduce ctx partials -> d_out ----
__global__ void ctx_reduce_kernel(const float* __restrict__ ctxp, float* __restrict__ ctx){
  int i = blockIdx.x * blockDim.x + threadIdx.x;   // 32768
  int b = i >> 9;
  int d = i & 511;
  float s = 0.f;
  #pragma unroll
  for (int sc = 0; sc < 8; ++sc) s += ctxp[((size_t)(b * 8 + sc)) * DD + d];
  ctx[(size_t)b * DD + d] = s;
}

extern "C" void kernel_launch(void* const* d_in, const int* in_sizes, int n_in,
                              void* d_out, int out_size, void* d_ws, size_t ws_size,
                              hipStream_t stream){
  const float* x  = (const float*)d_in[0];
  const float* W1 = (const float*)d_in[1];
  const float* b1 = (const float*)d_in[2];
  const float* w2 = (const float*)d_in[3];
  // d_in[4] = b2: softmax-invariant, unused.

  float* ctx  = (float*)d_out;                         // [64*512]
  float* wout = (float*)d_out + BB * DD;               // [64*2048]

  // ws layout (phase-disjoint reuse):
  //   scores phase: W1b [0, 512K), scorep [512K, 1M)
  //   ctx phase:    ctxp [0, 1M)  (W1b/scorep dead by then; same-stream order)
  unsigned short* W1b = (unsigned short*)d_ws;
  float* scorep = (float*)((char*)d_ws + (512u << 10));
  float* ctxp   = (float*)d_ws;

  hipLaunchKernelGGL(cvt_w1_kernel,      dim3(128),  dim3(256), 0, stream, W1, W1b);
  hipLaunchKernelGGL(scores_kernel,      dim3(2048), dim3(512), 0, stream, x, W1b, b1, w2, scorep);
  hipLaunchKernelGGL(softmax_kernel,     dim3(64),   dim3(256), 0, stream, scorep, wout);
  hipLaunchKernelGGL(ctx_partial_kernel, dim3(512),  dim3(512), 0, stream, x, wout, ctxp);
  hipLaunchKernelGGL(ctx_reduce_kernel,  dim3(128),  dim3(256), 0, stream, ctxp, ctx);
}

// Round 10
// 181.545 us; speedup vs baseline: 1.2149x; 1.2149x over previous
//
#include <hip/hip_runtime.h>
#include <hip/hip_bf16.h>

#define BB 64
#define SS 2048
#define DD 512
#define MTOT (BB * SS)          // 131072 rows

typedef __attribute__((ext_vector_type(8))) short short8;   // 8 bf16
typedef __attribute__((ext_vector_type(4))) float f32x4;

// fp32->bf16 RNE; compiler fuses pairs into v_cvt_pk_bf16_f32
__device__ __forceinline__ short f2bf(float f){
  __hip_bfloat16 h = __float2bfloat16(f);
  return *reinterpret_cast<short*>(&h);
}
__device__ __forceinline__ short8 pack8(float4 a, float4 b){
  short8 u;
  u[0]=f2bf(a.x); u[1]=f2bf(a.y); u[2]=f2bf(a.z); u[3]=f2bf(a.w);
  u[4]=f2bf(b.x); u[5]=f2bf(b.y); u[6]=f2bf(b.z); u[7]=f2bf(b.w);
  return u;
}
__device__ __forceinline__ void gload_lds16(const unsigned short* g, unsigned short* l){
  __builtin_amdgcn_global_load_lds(
      (const __attribute__((address_space(1))) unsigned int*)g,
      (__attribute__((address_space(3))) unsigned int*)l, 16, 0, 0);
}

// ---- kernel 1: W1 fp32 -> bf16, PRE-SWIZZLED per-step layout (R3-proven) ----
// granule (s,g): kc=g>>9, holds W1 row e=(g&511)^kc, k-elems [s*32+kc*8, +8).
__global__ void cvt_w1_kernel(const float* __restrict__ W1, unsigned short* __restrict__ W1s){
  int i = blockIdx.x * blockDim.x + threadIdx.x;   // 32768 = 16 steps * 2048 granules
  int s  = i >> 11;
  int g  = i & 2047;
  int kc = g >> 9;
  int e  = (g & 511) ^ kc;
  const float* src = W1 + (size_t)e * DD + s * 32 + kc * 8;
  float4 f0 = *(const float4*)src;
  float4 f1 = *(const float4*)(src + 4);
  *(short8*)(W1s + (size_t)i * 8) = pack8(f0, f1);
}

// ---- kernel 2: scores = sum_e tanh(x@W1^T + b1)[.,e] * w2[e] ----
// BM=128 (2x R3: 32 MFMA per wave per barrier-pair), BN=512, BK=32, 16 steps.
// 512 thr / 8 waves; wave tile 128 rows x 64 e -> acc[8][4] (128 AGPR).
// B: gload_lds double-buffer from pre-swizzled W1s (coalesced DMA; proven).
// A: all-512-thread reg staging depth-2 (issue A(s+2) at s, cvt+write at s+1),
//    swizzle kc ^ ((row>>1)&3) (R8-proven 0 conflicts).
// Barriers: raw s_barrier + lgkmcnt(0) + counted vmcnt(2) — B gloads (issued
// OLDEST) retire, A prefetch (issued newest) stays in flight across barrier.
__launch_bounds__(512, 2)
__global__ void scores_kernel(const float* __restrict__ x,
                              const unsigned short* __restrict__ W1s,
                              const float* __restrict__ b1,
                              const float* __restrict__ w2,
                              float* __restrict__ scorep){
  __shared__ __align__(16) unsigned short Bbuf[2][16384];  // 2 x 32KB
  __shared__ __align__(16) unsigned short Abuf[2][4096];   // 2 x 8KB (128x32 bf16)
  __shared__ float psum[8 * 128];

  const int t    = threadIdx.x;
  const int lane = t & 63;
  const int wid  = t >> 6;
  const int m0   = blockIdx.x * 128;
  const int arow = lane & 15;
  const int kgrp = lane >> 4;

  f32x4 acc[8][4];
  #pragma unroll
  for (int mt = 0; mt < 8; ++mt)
    #pragma unroll
    for (int et = 0; et < 4; ++et)
      acc[mt][et] = (f32x4){0.f, 0.f, 0.f, 0.f};

  // A staging: 512 threads, 2 float4/step. r=t>>2 (0..127), q=t&3 (8-elem granule)
  const int ar = t >> 2;
  const int aq = t & 3;
  const float* asrc = x + (size_t)(m0 + ar) * DD + aq * 8;
  const int awoff = ((ar << 2) + (aq ^ ((ar >> 1) & 3))) << 4;  // 16B granule

  // B staging: wave wid issues 4 gload_lds; source linear in pre-swizzled W1s
  const unsigned short* bsrc = W1s + ((size_t)((wid << 2) << 6) + lane) * 8;

  float4 areg[2][2];

  // ---- prologue: B(0) x4 (oldest); A(0) x2; A(1) x2 (newest); cvt A(0) ----
  #pragma unroll
  for (int j = 0; j < 4; ++j)
    gload_lds16(bsrc + j * 512, &Bbuf[0][((wid << 2) + j) * 512]);
  float4 p0 = *(const float4*)asrc;
  float4 p1 = *(const float4*)(asrc + 4);
  areg[1][0] = *(const float4*)(asrc + 32);
  areg[1][1] = *(const float4*)(asrc + 36);
  *(short8*)((char*)&Abuf[0][0] + awoff) = pack8(p0, p1);  // compiler waits A(0)
  asm volatile("s_waitcnt vmcnt(2)" ::: "memory");          // retire B(0); keep A(1)
  asm volatile("s_waitcnt lgkmcnt(0)" ::: "memory");
  __builtin_amdgcn_s_barrier();
  __builtin_amdgcn_sched_barrier(0);

  // ---- main loop: 16 k-steps of 32, fully unrolled ----
  #pragma unroll
  for (int s = 0; s < 16; ++s){
    // 1. issue B(s+1) gload_lds (OLDEST in vmem queue this step)
    if (s < 15){
      const unsigned short* bs = bsrc + (size_t)(s + 1) * 16384;
      #pragma unroll
      for (int j = 0; j < 4; ++j)
        gload_lds16(bs + j * 512, &Bbuf[(s + 1) & 1][((wid << 2) + j) * 512]);
    }
    // 2. issue A(s+2) reg loads (NEWEST; stay in flight across barrier)
    if (s < 14){
      areg[s & 1][0] = *(const float4*)(asrc + (s + 2) * 32);
      areg[s & 1][1] = *(const float4*)(asrc + (s + 2) * 32 + 4);
    }

    // 3. MFMA phase: per-mt af stream (low VGPR), bf[4] from Bbuf
    short8 bf[4];
    #pragma unroll
    for (int et = 0; et < 4; ++et){
      int e = (wid << 6) + (et << 4) + arow;
      bf[et] = *(const short8*)((char*)&Bbuf[s & 1][0] + (((kgrp << 9) + (e ^ kgrp)) << 4));
    }
    __builtin_amdgcn_s_setprio(1);
    #pragma unroll
    for (int mt = 0; mt < 8; ++mt){
      int row = mt * 16 + arow;
      short8 af = *(const short8*)((char*)&Abuf[s & 1][0]
                + (((row << 2) + (kgrp ^ ((row >> 1) & 3))) << 4));
      #pragma unroll
      for (int et = 0; et < 4; ++et)
        acc[mt][et] = __builtin_amdgcn_mfma_f32_16x16x32_bf16(af, bf[et], acc[mt][et], 0, 0, 0);
    }
    __builtin_amdgcn_s_setprio(0);

    // 4. cvt+write A(s+1) (loaded at s-1; compiler's counted wait ~free)
    if (s < 15)
      *(short8*)((char*)&Abuf[(s + 1) & 1][0] + awoff)
          = pack8(areg[(s + 1) & 1][0], areg[(s + 1) & 1][1]);

    // 5. counted-vmcnt barrier: retire B(s+1) gloads, keep A(s+2) in flight
    if (s < 15){
      if (s < 14) asm volatile("s_waitcnt vmcnt(2)" ::: "memory");
      else        asm volatile("s_waitcnt vmcnt(0)" ::: "memory");
      asm volatile("s_waitcnt lgkmcnt(0)" ::: "memory");
      __builtin_amdgcn_s_barrier();
      __builtin_amdgcn_sched_barrier(0);
    }
  }

  // ---- epilogue: tanh + dot(w2), reduce over e ----
  float ps[8][4];
  #pragma unroll
  for (int mt = 0; mt < 8; ++mt)
    #pragma unroll
    for (int i = 0; i < 4; ++i) ps[mt][i] = 0.f;

  #pragma unroll
  for (int et = 0; et < 4; ++et){
    int e = (wid << 6) + (et << 4) + arow;     // C/D col = lane&15
    float b1v = b1[e];
    float w2v = w2[e];
    #pragma unroll
    for (int mt = 0; mt < 8; ++mt){
      #pragma unroll
      for (int i = 0; i < 4; ++i){
        float g = acc[mt][et][i] + b1v;
        g = fminf(15.f, fmaxf(-15.f, g));
        float ex = __expf(2.f * g);
        ps[mt][i] += (1.f - 2.f / (ex + 1.f)) * w2v;   // tanh(g)*w2
      }
    }
  }
  #pragma unroll
  for (int mt = 0; mt < 8; ++mt)
    #pragma unroll
    for (int i = 0; i < 4; ++i){
      float v = ps[mt][i];
      v += __shfl_xor(v, 1);
      v += __shfl_xor(v, 2);
      v += __shfl_xor(v, 4);
      v += __shfl_xor(v, 8);
      ps[mt][i] = v;
    }
  if ((lane & 15) == 0){
    #pragma unroll
    for (int mt = 0; mt < 8; ++mt)
      #pragma unroll
      for (int i = 0; i < 4; ++i)
        psum[wid * 128 + mt * 16 + (lane >> 4) * 4 + i] = ps[mt][i];
  }
  __syncthreads();
  if (t < 128){
    float ssum = 0.f;
    #pragma unroll
    for (int w = 0; w < 8; ++w) ssum += psum[w * 128 + t];
    scorep[m0 + t] = ssum;    // pre-softmax; b2 softmax-invariant
  }
}

// ---- kernel 3: row softmax -> w ----
__global__ void softmax_kernel(const float* __restrict__ scorep, float* __restrict__ wout){
  const int b = blockIdx.x;
  const int t = threadIdx.x;                 // 256
  float v[8];
  #pragma unroll
  for (int i = 0; i < 8; ++i) v[i] = scorep[(size_t)b * SS + t + i * 256];
  float m = v[0];
  #pragma unroll
  for (int i = 1; i < 8; ++i) m = fmaxf(m, v[i]);
  #pragma unroll
  for (int msk = 32; msk >= 1; msk >>= 1) m = fmaxf(m, __shfl_xor(m, msk));
  __shared__ float redm[4], reds[4];
  if ((t & 63) == 0) redm[t >> 6] = m;
  __syncthreads();
  m = fmaxf(fmaxf(redm[0], redm[1]), fmaxf(redm[2], redm[3]));
  float s = 0.f;
  #pragma unroll
  for (int i = 0; i < 8; ++i){ v[i] = __expf(v[i] - m); s += v[i]; }
  #pragma unroll
  for (int msk = 32; msk >= 1; msk >>= 1) s += __shfl_xor(s, msk);
  if ((t & 63) == 0) reds[t >> 6] = s;
  __syncthreads();
  s = reds[0] + reds[1] + reds[2] + reds[3];
  float inv = 1.f / s;
  #pragma unroll
  for (int i = 0; i < 8; ++i) wout[(size_t)b * SS + t + i * 256] = v[i] * inv;
}

// ---- kernel 4: ctx partials (fp32 x, no atomics; at HBM floor) ----
__global__ void ctx_partial_kernel(const float* __restrict__ x, const float* __restrict__ wout,
                                   float* __restrict__ ctxp){
  __shared__ float red[4][512];
  const int t   = threadIdx.x;
  const int sub = t >> 7;                    // 0..3 (wave-uniform)
  const int dt  = t & 127;                   // d = dt*4
  const int b   = blockIdx.x >> 3;
  const int sc  = blockIdx.x & 7;
  const float* xb = x + (size_t)b * SS * DD;
  const int s0 = sc * 256 + sub * 64;
  float4 acc = {0.f, 0.f, 0.f, 0.f};
  for (int s = s0; s < s0 + 64; ++s){
    float wv = wout[(size_t)b * SS + s];     // wave-uniform -> scalar load
    float4 xv = *(const float4*)(xb + (size_t)s * DD + dt * 4);
    acc.x += wv * xv.x; acc.y += wv * xv.y; acc.z += wv * xv.z; acc.w += wv * xv.w;
  }
  *(float4*)&red[sub][dt * 4] = acc;
  __syncthreads();
  if (t < 128){
    float4 r0 = *(const float4*)&red[0][t * 4];
    float4 r1 = *(const float4*)&red[1][t * 4];
    float4 r2 = *(const float4*)&red[2][t * 4];
    float4 r3 = *(const float4*)&red[3][t * 4];
    float4 o = { r0.x+r1.x+r2.x+r3.x, r0.y+r1.y+r2.y+r3.y,
                 r0.z+r1.z+r2.z+r3.z, r0.w+r1.w+r2.w+r3.w };
    *(float4*)&ctxp[((size_t)(b * 8 + sc)) * DD + t * 4] = o;
  }
}

// ---- kernel 5: reduce ctx partials -> d_out ----
__global__ void ctx_reduce_kernel(const float* __restrict__ ctxp, float* __restrict__ ctx){
  int i = blockIdx.x * blockDim.x + threadIdx.x;   // 32768
  int b = i >> 9;
  int d = i & 511;
  float s = 0.f;
  #pragma unroll
  for (int sc = 0; sc < 8; ++sc) s += ctxp[((size_t)(b * 8 + sc)) * DD + d];
  ctx[(size_t)b * DD + d] = s;
}

extern "C" void kernel_launch(void* const* d_in, const int* in_sizes, int n_in,
                              void* d_out, int out_size, void* d_ws, size_t ws_size,
                              hipStream_t stream){
  const float* x  = (const float*)d_in[0];
  const float* W1 = (const float*)d_in[1];
  const float* b1 = (const float*)d_in[2];
  const float* w2 = (const float*)d_in[3];
  // d_in[4] = b2: softmax-invariant, unused.

  float* ctx  = (float*)d_out;                         // [64*512]
  float* wout = (float*)d_out + BB * DD;               // [64*2048]

  // ws layout (phase-disjoint reuse):
  //   scores phase: W1s [0, 512K), scorep [512K, 1M)
  //   ctx phase:    ctxp [0, 1M)  (W1s/scorep dead by then; same-stream order)
  unsigned short* W1s = (unsigned short*)d_ws;
  float* scorep = (float*)((char*)d_ws + (512u << 10));
  float* ctxp   = (float*)d_ws;

  hipLaunchKernelGGL(cvt_w1_kernel,      dim3(128),  dim3(256), 0, stream, W1, W1s);
  hipLaunchKernelGGL(scores_kernel,      dim3(1024), dim3(512), 0, stream, x, W1s, b1, w2, scorep);
  hipLaunchKernelGGL(softmax_kernel,     dim3(64),   dim3(256), 0, stream, scorep, wout);
  hipLaunchKernelGGL(ctx_partial_kernel, dim3(512),  dim3(512), 0, stream, x, wout, ctxp);
  hipLaunchKernelGGL(ctx_reduce_kernel,  dim3(128),  dim3(256), 0, stream, ctxp, ctx);
}

// Round 11
// 174.232 us; speedup vs baseline: 1.2659x; 1.0420x over previous
//
#include <hip/hip_runtime.h>
#include <hip/hip_bf16.h>

#define BB 64
#define SS 2048
#define DD 512
#define MTOT (BB * SS)          // 131072 rows

typedef __attribute__((ext_vector_type(8))) short short8;   // 8 bf16
typedef __attribute__((ext_vector_type(4))) float f32x4;

// fp32->bf16 RNE; compiler fuses pairs into v_cvt_pk_bf16_f32
__device__ __forceinline__ short f2bf(float f){
  __hip_bfloat16 h = __float2bfloat16(f);
  return *reinterpret_cast<short*>(&h);
}
__device__ __forceinline__ short8 pack8(float4 a, float4 b){
  short8 u;
  u[0]=f2bf(a.x); u[1]=f2bf(a.y); u[2]=f2bf(a.z); u[3]=f2bf(a.w);
  u[4]=f2bf(b.x); u[5]=f2bf(b.y); u[6]=f2bf(b.z); u[7]=f2bf(b.w);
  return u;
}
__device__ __forceinline__ void gload_lds16(const unsigned short* g, unsigned short* l){
  __builtin_amdgcn_global_load_lds(
      (const __attribute__((address_space(1))) unsigned int*)g,
      (__attribute__((address_space(3))) unsigned int*)l, 16, 0, 0);
}

// ---- kernel 1: W1 fp32 -> bf16, PRE-SWIZZLED [ec][step][granule] layout ----
// Within (ec,s): 1024 granules of 8 bf16. granule g: kc=g>>8, el=(g&255)^kc,
// holds W1 row e=ec*256+el, k-elems [s*32+kc*8, +8).
__global__ void cvt_w1_kernel(const float* __restrict__ W1, unsigned short* __restrict__ W1s){
  int i = blockIdx.x * blockDim.x + threadIdx.x;   // 32768 = 2 ec * 16 steps * 1024 granules
  int ec  = i >> 14;
  int rem = i & 16383;
  int s   = rem >> 10;
  int g   = rem & 1023;
  int kc  = g >> 8;
  int el  = (g & 255) ^ kc;
  int e   = (ec << 8) + el;
  const float* src = W1 + (size_t)e * DD + s * 32 + kc * 8;
  float4 f0 = *(const float4*)src;
  float4 f1 = *(const float4*)(src + 4);
  *(short8*)(W1s + (size_t)i * 8) = pack8(f0, f1);
}

// ---- kernel 2: partial scores over one 256-wide e-chunk ----
// BM=128, BN=256, BK=32, 16 steps, 512 thr / 8 waves.
// Wave wid owns e_local in [wid*32,+32): tile 128x32 -> acc[8][2] (64 AGPR).
// B: gload_lds double-buffer, 16KB/step (HALVED vs R3 - the DMA-rate lever).
// A: all-512-thread reg staging depth-2, swizzle aq^((ar>>1)&3) (0 conflicts).
// Barriers: raw s_barrier + lgkmcnt(0) + counted vmcnt(2).
// LDS 52KB, 64 VGPR + 64 AGPR -> 2 blocks/CU.
__launch_bounds__(512, 4)
__global__ void scores_kernel(const float* __restrict__ x,
                              const unsigned short* __restrict__ W1s,
                              const float* __restrict__ b1,
                              const float* __restrict__ w2,
                              float* __restrict__ scorep){
  __shared__ __align__(16) unsigned short Bbuf[2][8192];   // 2 x 16KB
  __shared__ __align__(16) unsigned short Abuf[2][4096];   // 2 x 8KB (128x32 bf16)
  __shared__ float psum[8 * 128];

  const int t    = threadIdx.x;
  const int lane = t & 63;
  const int wid  = t >> 6;
  const int ec   = blockIdx.x & 1;
  const int m0   = (blockIdx.x >> 1) * 128;
  const int arow = lane & 15;
  const int kgrp = lane >> 4;

  f32x4 acc[8][2];
  #pragma unroll
  for (int mt = 0; mt < 8; ++mt)
    #pragma unroll
    for (int et = 0; et < 2; ++et)
      acc[mt][et] = (f32x4){0.f, 0.f, 0.f, 0.f};

  // A staging: 512 threads, 2 float4/step. ar=t>>2 (0..127), aq=t&3 (8-elem granule)
  const int ar = t >> 2;
  const int aq = t & 3;
  const float* asrc = x + (size_t)(m0 + ar) * DD + aq * 8;
  const int awoff = ((ar << 2) + (aq ^ ((ar >> 1) & 3))) << 4;

  // B staging: wave wid stages granules [wid*128,+128) per step (2 gload_lds)
  const unsigned short* bsrc = W1s + ((size_t)ec * 131072) + ((size_t)(wid << 7) + lane) * 8;

  float4 areg[2][2];

  // ---- prologue: B(0) x2 (oldest); A(0) x2; A(1) x2 (newest); cvt A(0) ----
  #pragma unroll
  for (int j = 0; j < 2; ++j)
    gload_lds16(bsrc + j * 512, &Bbuf[0][((wid << 1) + j) * 512]);
  float4 p0 = *(const float4*)asrc;
  float4 p1 = *(const float4*)(asrc + 4);
  areg[1][0] = *(const float4*)(asrc + 32);
  areg[1][1] = *(const float4*)(asrc + 36);
  *(short8*)((char*)&Abuf[0][0] + awoff) = pack8(p0, p1);  // compiler waits A(0)
  asm volatile("s_waitcnt vmcnt(2)" ::: "memory");          // retire B(0); keep A(1)
  asm volatile("s_waitcnt lgkmcnt(0)" ::: "memory");
  __builtin_amdgcn_s_barrier();
  __builtin_amdgcn_sched_barrier(0);

  // ---- main loop: 16 k-steps of 32, fully unrolled ----
  #pragma unroll
  for (int s = 0; s < 16; ++s){
    // 1. issue B(s+1) gload_lds (OLDEST in vmem queue this step)
    if (s < 15){
      const unsigned short* bs = bsrc + (size_t)(s + 1) * 8192;
      #pragma unroll
      for (int j = 0; j < 2; ++j)
        gload_lds16(bs + j * 512, &Bbuf[(s + 1) & 1][((wid << 1) + j) * 512]);
    }
    // 2. issue A(s+2) reg loads (NEWEST; stay in flight across barrier)
    if (s < 14){
      areg[s & 1][0] = *(const float4*)(asrc + (s + 2) * 32);
      areg[s & 1][1] = *(const float4*)(asrc + (s + 2) * 32 + 4);
    }

    // 3. MFMA phase
    short8 bf[2];
    #pragma unroll
    for (int et = 0; et < 2; ++et){
      int el = (wid << 5) + (et << 4) + arow;   // e_local 0..255
      bf[et] = *(const short8*)((char*)&Bbuf[s & 1][0] + (((kgrp << 8) + (el ^ kgrp)) << 4));
    }
    __builtin_amdgcn_s_setprio(1);
    #pragma unroll
    for (int mt = 0; mt < 8; ++mt){
      int row = mt * 16 + arow;
      short8 af = *(const short8*)((char*)&Abuf[s & 1][0]
                + (((row << 2) + (kgrp ^ ((row >> 1) & 3))) << 4));
      #pragma unroll
      for (int et = 0; et < 2; ++et)
        acc[mt][et] = __builtin_amdgcn_mfma_f32_16x16x32_bf16(af, bf[et], acc[mt][et], 0, 0, 0);
    }
    __builtin_amdgcn_s_setprio(0);

    // 4. cvt+write A(s+1) (loaded at s-1; counted wait ~free)
    if (s < 15)
      *(short8*)((char*)&Abuf[(s + 1) & 1][0] + awoff)
          = pack8(areg[(s + 1) & 1][0], areg[(s + 1) & 1][1]);

    // 5. counted-vmcnt barrier: retire B(s+1), keep A(s+2) in flight
    if (s < 15){
      if (s < 14) asm volatile("s_waitcnt vmcnt(2)" ::: "memory");
      else        asm volatile("s_waitcnt vmcnt(0)" ::: "memory");
      asm volatile("s_waitcnt lgkmcnt(0)" ::: "memory");
      __builtin_amdgcn_s_barrier();
      __builtin_amdgcn_sched_barrier(0);
    }
  }

  // ---- epilogue: tanh + dot(w2), reduce over e ----
  float ps[8][2];
  #pragma unroll
  for (int mt = 0; mt < 8; ++mt)
    #pragma unroll
    for (int i = 0; i < 2; ++i) ps[mt][i] = 0.f;
  // note: ps[mt][i] holds row-pair partials; accumulate over et and acc-lane i below
  float psf[8][4];
  #pragma unroll
  for (int mt = 0; mt < 8; ++mt)
    #pragma unroll
    for (int i = 0; i < 4; ++i) psf[mt][i] = 0.f;

  #pragma unroll
  for (int et = 0; et < 2; ++et){
    int e = (ec << 8) + (wid << 5) + (et << 4) + arow;   // global e; C/D col = lane&15
    float b1v = b1[e];
    float w2v = w2[e];
    #pragma unroll
    for (int mt = 0; mt < 8; ++mt){
      #pragma unroll
      for (int i = 0; i < 4; ++i){
        float g = acc[mt][et][i] + b1v;
        g = fminf(15.f, fmaxf(-15.f, g));
        float ex = __expf(2.f * g);
        psf[mt][i] += (1.f - 2.f / (ex + 1.f)) * w2v;   // tanh(g)*w2
      }
    }
  }
  #pragma unroll
  for (int mt = 0; mt < 8; ++mt)
    #pragma unroll
    for (int i = 0; i < 4; ++i){
      float v = psf[mt][i];
      v += __shfl_xor(v, 1);
      v += __shfl_xor(v, 2);
      v += __shfl_xor(v, 4);
      v += __shfl_xor(v, 8);
      psf[mt][i] = v;
    }
  if ((lane & 15) == 0){
    #pragma unroll
    for (int mt = 0; mt < 8; ++mt)
      #pragma unroll
      for (int i = 0; i < 4; ++i)
        psum[wid * 128 + mt * 16 + (lane >> 4) * 4 + i] = psf[mt][i];
  }
  __syncthreads();
  if (t < 128){
    float ssum = 0.f;
    #pragma unroll
    for (int w = 0; w < 8; ++w) ssum += psum[w * 128 + t];
    scorep[(size_t)ec * MTOT + m0 + t] = ssum;   // e-chunk partial; b2 softmax-invariant
  }
}

// ---- kernel 3: sum e-chunk partials + row softmax -> w ----
__global__ void softmax_kernel(const float* __restrict__ scorep, float* __restrict__ wout){
  const int b = blockIdx.x;
  const int t = threadIdx.x;                 // 256
  float v[8];
  #pragma unroll
  for (int i = 0; i < 8; ++i){
    int m = b * SS + t + i * 256;
    v[i] = scorep[m] + scorep[MTOT + m];
  }
  float m = v[0];
  #pragma unroll
  for (int i = 1; i < 8; ++i) m = fmaxf(m, v[i]);
  #pragma unroll
  for (int msk = 32; msk >= 1; msk >>= 1) m = fmaxf(m, __shfl_xor(m, msk));
  __shared__ float redm[4], reds[4];
  if ((t & 63) == 0) redm[t >> 6] = m;
  __syncthreads();
  m = fmaxf(fmaxf(redm[0], redm[1]), fmaxf(redm[2], redm[3]));
  float s = 0.f;
  #pragma unroll
  for (int i = 0; i < 8; ++i){ v[i] = __expf(v[i] - m); s += v[i]; }
  #pragma unroll
  for (int msk = 32; msk >= 1; msk >>= 1) s += __shfl_xor(s, msk);
  if ((t & 63) == 0) reds[t >> 6] = s;
  __syncthreads();
  s = reds[0] + reds[1] + reds[2] + reds[3];
  float inv = 1.f / s;
  #pragma unroll
  for (int i = 0; i < 8; ++i) wout[(size_t)b * SS + t + i * 256] = v[i] * inv;
}

// ---- kernel 4: ctx partials (fp32 x, no atomics; at HBM floor) ----
__global__ void ctx_partial_kernel(const float* __restrict__ x, const float* __restrict__ wout,
                                   float* __restrict__ ctxp){
  __shared__ float red[4][512];
  const int t   = threadIdx.x;
  const int sub = t >> 7;                    // 0..3 (wave-uniform)
  const int dt  = t & 127;                   // d = dt*4
  const int b   = blockIdx.x >> 3;
  const int sc  = blockIdx.x & 7;
  const float* xb = x + (size_t)b * SS * DD;
  const int s0 = sc * 256 + sub * 64;
  float4 acc = {0.f, 0.f, 0.f, 0.f};
  for (int s = s0; s < s0 + 64; ++s){
    float wv = wout[(size_t)b * SS + s];     // wave-uniform -> scalar load
    float4 xv = *(const float4*)(xb + (size_t)s * DD + dt * 4);
    acc.x += wv * xv.x; acc.y += wv * xv.y; acc.z += wv * xv.z; acc.w += wv * xv.w;
  }
  *(float4*)&red[sub][dt * 4] = acc;
  __syncthreads();
  if (t < 128){
    float4 r0 = *(const float4*)&red[0][t * 4];
    float4 r1 = *(const float4*)&red[1][t * 4];
    float4 r2 = *(const float4*)&red[2][t * 4];
    float4 r3 = *(const float4*)&red[3][t * 4];
    float4 o = { r0.x+r1.x+r2.x+r3.x, r0.y+r1.y+r2.y+r3.y,
                 r0.z+r1.z+r2.z+r3.z, r0.w+r1.w+r2.w+r3.w };
    *(float4*)&ctxp[((size_t)(b * 8 + sc)) * DD + t * 4] = o;
  }
}

// ---- kernel 5: reduce ctx partials -> d_out ----
__global__ void ctx_reduce_kernel(const float* __restrict__ ctxp, float* __restrict__ ctx){
  int i = blockIdx.x * blockDim.x + threadIdx.x;   // 32768
  int b = i >> 9;
  int d = i & 511;
  float s = 0.f;
  #pragma unroll
  for (int sc = 0; sc < 8; ++sc) s += ctxp[((size_t)(b * 8 + sc)) * DD + d];
  ctx[(size_t)b * DD + d] = s;
}

extern "C" void kernel_launch(void* const* d_in, const int* in_sizes, int n_in,
                              void* d_out, int out_size, void* d_ws, size_t ws_size,
                              hipStream_t stream){
  const float* x  = (const float*)d_in[0];
  const float* W1 = (const float*)d_in[1];
  const float* b1 = (const float*)d_in[2];
  const float* w2 = (const float*)d_in[3];
  // d_in[4] = b2: softmax-invariant, unused.

  float* ctx  = (float*)d_out;                         // [64*512]
  float* wout = (float*)d_out + BB * DD;               // [64*2048]

  // ws layout:
  //   scores phase: W1s [0,512K), scorep [512K, 1.5M)  (2 e-chunks x 512K)
  //   ctx phase:    ctxp [0, 1M)  (W1s + scorep[ec=0] dead by then)
  unsigned short* W1s = (unsigned short*)d_ws;
  float* scorep = (float*)((char*)d_ws + (512u << 10));
  float* ctxp   = (float*)d_ws;

  hipLaunchKernelGGL(cvt_w1_kernel,      dim3(128),  dim3(256), 0, stream, W1, W1s);
  hipLaunchKernelGGL(scores_kernel,      dim3(2048), dim3(512), 0, stream, x, W1s, b1, w2, scorep);
  hipLaunchKernelGGL(softmax_kernel,     dim3(64),   dim3(256), 0, stream, scorep, wout);
  hipLaunchKernelGGL(ctx_partial_kernel, dim3(512),  dim3(512), 0, stream, x, wout, ctxp);
  hipLaunchKernelGGL(ctx_reduce_kernel,  dim3(128),  dim3(256), 0, stream, ctxp, ctx);
}